// Round 11
// baseline (389.191 us; speedup 1.0000x reference)
//
#include <hip/hip_runtime.h>

#define N_NODES 40000
#define N_EDGES 640000
#define N_REL   8
#define H_DIM   128
#define C_DIM   64
#define NR      (N_NODES * N_REL)        // 320000 segments
#define SCAN_NB ((NR + 1023) / 1024)     // 313 scan blocks
#define EDGE_NB  (N_EDGES / 256)         // 2500
#define W1CVT_NB ((N_REL * N_NODES * H_DIM / 4) / 256)   // 40000
#define W2CVT_NB (9 * C_DIM * H_DIM / 256)               // 288

typedef __attribute__((ext_vector_type(8))) short bf16x8;
typedef __attribute__((ext_vector_type(4))) float f32x4;

__device__ inline uint rne_bf16(float x) {
    uint u = __float_as_uint(x);
    return (u + 0x7FFFu + ((u >> 16) & 1u)) >> 16;
}
__device__ inline uint pack_bf16(float x, float y) {   // x -> low half
    return rne_bf16(x) | (rne_bf16(y) << 16);
}
__device__ inline float bf_lo(uint v) { return __uint_as_float(v << 16); }
__device__ inline float bf_hi(uint v) { return __uint_as_float(v & 0xFFFF0000u); }

// ---- fused: count+rank (edge blocks) | W1->bf16 (stream blocks) | W2 prep ----
__global__ __launch_bounds__(256) void
build_convert(const int* __restrict__ ei, const int* __restrict__ et,
              int* __restrict__ cnt, int* __restrict__ rank,
              const float* __restrict__ W1, ushort* __restrict__ w1b,
              const float* __restrict__ W2, const float* __restrict__ root2,
              ushort* __restrict__ w2t) {
    int b = blockIdx.x, t = threadIdx.x;
    if (b < EDGE_NB) {
        int e = b * 256 + t;
        int seg = ei[N_EDGES + e] * N_REL + et[e];
        rank[e] = atomicAdd(&cnt[seg], 1);     // old value = rank; cnt ends = count
    } else if (b < EDGE_NB + W1CVT_NB) {
        long i = (long)(b - EDGE_NB) * 256 + t;   // float4 index over R*N*H/4
        float4 v = ((const float4*)W1)[i];
        uint2 o; o.x = pack_bf16(v.x, v.y); o.y = pack_bf16(v.z, v.w);
        ((uint2*)w1b)[i] = o;
    } else {
        int i = (b - EDGE_NB - W1CVT_NB) * 256 + t;   // 9*64*128
        int k = i & 127; int c = (i >> 7) & 63; int r = i >> 13;
        float v = (r < 8) ? W2[((size_t)r * H_DIM + k) * C_DIM + c]
                          : root2[(size_t)k * C_DIM + c];
        int byte = (c * 256 + k * 2) ^ ((c & 7) << 4);   // XOR-swizzle (T2)
        w2t[(size_t)r * 8192 + (byte >> 1)] = (ushort)rne_bf16(v);
    }
}

// ---------------- multi-block exclusive scan over NR (coalesced) ----------------
__global__ void scanA(const int* __restrict__ cnt, int* __restrict__ segbase,
                      int* __restrict__ bsum) {
    __shared__ int lds[256];
    int base = blockIdx.x * 1024;
    int t = threadIdx.x;
    int v[4]; int s = 0;
    #pragma unroll
    for (int j = 0; j < 4; j++) {
        int idx = base + t * 4 + j;
        v[j] = (idx < NR) ? cnt[idx] : 0;
        s += v[j];
    }
    lds[t] = s; __syncthreads();
    int x = s;
    #pragma unroll
    for (int off = 1; off < 256; off <<= 1) {
        int y = (t >= off) ? lds[t - off] : 0;
        __syncthreads();
        x += y; lds[t] = x;
        __syncthreads();
    }
    int excl = x - s;
    #pragma unroll
    for (int j = 0; j < 4; j++) {
        int idx = base + t * 4 + j;
        if (idx < NR) segbase[idx] = excl;
        excl += v[j];
    }
    if (t == 255) bsum[blockIdx.x] = x;
}

__global__ __launch_bounds__(512) void
scanB(int* __restrict__ bsum, int* __restrict__ segbase) {
    __shared__ int lds[512];
    int t = threadIdx.x;
    int v = (t < SCAN_NB) ? bsum[t] : 0;
    lds[t] = v; __syncthreads();
    int x = v;
    for (int off = 1; off < 512; off <<= 1) {
        int y = (t >= off) ? lds[t - off] : 0;
        __syncthreads();
        x += y; lds[t] = x;
        __syncthreads();
    }
    if (t < SCAN_NB) bsum[t] = x - v;          // exclusive block offset
    if (t == 511) segbase[NR] = x;             // total == N_EDGES (sentinel)
}

__global__ void scanC(int* __restrict__ segbase, const int* __restrict__ bsum) {
    int idx = blockIdx.x * blockDim.x + threadIdx.x;
    if (idx < NR) segbase[idx] += bsum[idx >> 10];
}

// ---------------- scatter (atomic-free): em[segbase[seg]+rank[e]] ----------------
__global__ void scatter_kernel(const int* __restrict__ ei, const int* __restrict__ et,
                               const int* __restrict__ segbase,
                               const int* __restrict__ rank, int* __restrict__ em) {
    int e = blockIdx.x * blockDim.x + threadIdx.x;
    if (e < N_EDGES) {
        int r = et[e];
        int seg = ei[N_EDGES + e] * N_REL + r;
        em[segbase[seg] + rank[e]] = ei[e] | (r << 16);
    }
}

// ---------------- conv1: 1 wave/node, half-wave bf16 rows (256B), 8 in flight --
// h[n] = relu( sum_e (1/cnt[dst,r_e]) * W1b[r_e, src_e, :] + root1[n] + b1 )
// Weights from per-wave inv-table via wave-uniform-shape __shfl (all lanes active).
__global__ __launch_bounds__(256) void
conv1_gather(const int* __restrict__ em, const int* __restrict__ segbase,
             const int* __restrict__ cnt, const ushort* __restrict__ w1b,
             const float* __restrict__ root1, const float* __restrict__ b1,
             uint* __restrict__ h16) {
    int lane = threadIdx.x & 63, wv = threadIdx.x >> 6;
    int eg = lane >> 5, q = lane & 31;     // edge-group, uint2 index in 256B row
    int n = blockIdx.x * 4 + wv;
    int e0 = segbase[n * N_REL], e1 = segbase[n * N_REL + N_REL];
    int c = (lane < N_REL) ? cnt[n * N_REL + lane] : 1;
    float invreg = 1.0f / (float)((c > 0) ? c : 1);    // lane r holds 1/cnt[n,r]
    float4 acc = make_float4(0.f, 0.f, 0.f, 0.f);
    for (int base = e0; base < e1; base += 64) {
        int m = e1 - base; if (m > 64) m = 64;
        int md = (lane < m) ? em[base + lane] : 0;
        int i = 0;
        for (; i + 8 <= m; i += 8) {
            int i0 = i + eg, i1 = i0 + 2, i2 = i0 + 4, i3 = i0 + 6;
            int p0 = __shfl(md, i0), p1 = __shfl(md, i1);
            int p2 = __shfl(md, i2), p3 = __shfl(md, i3);
            float w0 = __shfl(invreg, p0 >> 16);
            float w1 = __shfl(invreg, p1 >> 16);
            float w2 = __shfl(invreg, p2 >> 16);
            float w3 = __shfl(invreg, p3 >> 16);
            uint2 v0 = ((const uint2*)(w1b + ((size_t)(p0 >> 16) * N_NODES + (p0 & 0xFFFF)) * H_DIM))[q];
            uint2 v1 = ((const uint2*)(w1b + ((size_t)(p1 >> 16) * N_NODES + (p1 & 0xFFFF)) * H_DIM))[q];
            uint2 v2 = ((const uint2*)(w1b + ((size_t)(p2 >> 16) * N_NODES + (p2 & 0xFFFF)) * H_DIM))[q];
            uint2 v3 = ((const uint2*)(w1b + ((size_t)(p3 >> 16) * N_NODES + (p3 & 0xFFFF)) * H_DIM))[q];
            acc.x += w0 * bf_lo(v0.x) + w1 * bf_lo(v1.x) + w2 * bf_lo(v2.x) + w3 * bf_lo(v3.x);
            acc.y += w0 * bf_hi(v0.x) + w1 * bf_hi(v1.x) + w2 * bf_hi(v2.x) + w3 * bf_hi(v3.x);
            acc.z += w0 * bf_lo(v0.y) + w1 * bf_lo(v1.y) + w2 * bf_lo(v2.y) + w3 * bf_lo(v3.y);
            acc.w += w0 * bf_hi(v0.y) + w1 * bf_hi(v1.y) + w2 * bf_hi(v2.y) + w3 * bf_hi(v3.y);
        }
        for (; i < m; i += 2) {
            int ii = i + eg;
            int srcl = (ii < m) ? ii : 0;
            int p = __shfl(md, srcl);
            float w = __shfl(invreg, p >> 16);
            if (ii < m) {
                uint2 v = ((const uint2*)(w1b + ((size_t)(p >> 16) * N_NODES + (p & 0xFFFF)) * H_DIM))[q];
                acc.x += w * bf_lo(v.x); acc.y += w * bf_hi(v.x);
                acc.z += w * bf_lo(v.y); acc.w += w * bf_hi(v.y);
            }
        }
    }
    acc.x += __shfl_xor(acc.x, 32);
    acc.y += __shfl_xor(acc.y, 32);
    acc.z += __shfl_xor(acc.z, 32);
    acc.w += __shfl_xor(acc.w, 32);
    if (eg == 0) {
        float4 rt = ((const float4*)root1)[(size_t)n * 32 + q];
        float4 bb = ((const float4*)b1)[q];
        float cx = fmaxf(acc.x + rt.x + bb.x, 0.f);
        float cy = fmaxf(acc.y + rt.y + bb.y, 0.f);
        float cz = fmaxf(acc.z + rt.z + bb.z, 0.f);
        float cw = fmaxf(acc.w + rt.w + bb.w, 0.f);
        uint2 o; o.x = pack_bf16(cx, cy); o.y = pack_bf16(cz, cw);
        ((uint2*)h16)[(size_t)n * 32 + q] = o;
    }
}

// ---------------- zgemm: Z[r] = h @ W2[r] (bf16), out = h @ root2 + b2 ---------
__global__ __launch_bounds__(256) void
zgemm(const uint* __restrict__ h16, const ushort* __restrict__ w2t,
      const float* __restrict__ b2, ushort* __restrict__ zb, float* __restrict__ out) {
    __shared__ uint ldsA[4096];   // 64 rows x 256B swizzled
    __shared__ uint ldsB[4096];
    int t = threadIdx.x, lane = t & 63, wv = t >> 6;
    int nbase = blockIdx.x * 64;
    for (int i = t; i < 4096; i += 256) {
        int row = i >> 6, cu = i & 63;
        int byte = (row * 256 + cu * 4) ^ ((row & 7) << 4);
        ldsA[byte >> 2] = h16[(size_t)(nbase + row) * 64 + cu];
    }
    const char* pA = (const char*)ldsA;
    const char* pB = (const char*)ldsB;
    int arow = wv * 16 + (lane & 15);
    int qk = (lane >> 4) * 16;
    for (int rr = 0; rr < 9; rr++) {
        __syncthreads();   // covers A staging and ldsB reuse
        const uint4* bsrc = (const uint4*)(w2t + (size_t)rr * 8192);
        ((uint4*)ldsB)[t]       = bsrc[t];
        ((uint4*)ldsB)[t + 256] = bsrc[t + 256];
        ((uint4*)ldsB)[t + 512] = bsrc[t + 512];
        ((uint4*)ldsB)[t + 768] = bsrc[t + 768];
        __syncthreads();
        f32x4 acc[4];
        #pragma unroll
        for (int ct = 0; ct < 4; ct++) acc[ct] = (f32x4){0.f, 0.f, 0.f, 0.f};
        #pragma unroll
        for (int ct = 0; ct < 4; ct++) {
            int bcol = ct * 16 + (lane & 15);
            #pragma unroll
            for (int kf = 0; kf < 4; kf++) {
                int abyte = (arow * 256 + kf * 64 + qk) ^ ((arow & 7) << 4);
                int bbyte = (bcol * 256 + kf * 64 + qk) ^ ((bcol & 7) << 4);
                bf16x8 a = *(const bf16x8*)(pA + abyte);
                bf16x8 b = *(const bf16x8*)(pB + bbyte);
                acc[ct] = __builtin_amdgcn_mfma_f32_16x16x32_bf16(a, b, acc[ct], 0, 0, 0);
            }
        }
        #pragma unroll
        for (int ct = 0; ct < 4; ct++) {
            int c = ct * 16 + (lane & 15);
            #pragma unroll
            for (int j = 0; j < 4; j++) {
                int n = nbase + wv * 16 + (lane >> 4) * 4 + j;
                if (rr < 8)
                    zb[((size_t)rr * N_NODES + n) * 64 + c] = (ushort)rne_bf16(acc[ct][j]);
                else
                    out[(size_t)n * 64 + c] = acc[ct][j] + b2[c];
            }
        }
    }
}

// ---------------- zgather: out[n] += sum_e w_e * Z[r_e, src_e, :] --------------
__global__ __launch_bounds__(256) void
zgather(const int* __restrict__ em, const int* __restrict__ segbase,
        const int* __restrict__ cnt, const uint* __restrict__ zb32,
        float* __restrict__ out) {
    int lane = threadIdx.x & 63, wv = threadIdx.x >> 6;
    int n = blockIdx.x * 4 + wv;
    int eg = lane >> 5, c2 = lane & 31;
    int e0 = segbase[n * N_REL], e1 = segbase[n * N_REL + N_REL];
    int c = (lane < N_REL) ? cnt[n * N_REL + lane] : 1;
    float invreg = 1.0f / (float)((c > 0) ? c : 1);
    float ax = 0.f, ay = 0.f;
    for (int base = e0; base < e1; base += 64) {
        int m = e1 - base; if (m > 64) m = 64;
        int md = (lane < m) ? em[base + lane] : 0;
        int i = 0;
        for (; i + 16 <= m; i += 16) {
            #pragma unroll
            for (int u = 0; u < 2; u++) {
                int j0 = i + u * 8 + eg, j1 = j0 + 2, j2 = j0 + 4, j3 = j0 + 6;
                int p0 = __shfl(md, j0), p1 = __shfl(md, j1);
                int p2 = __shfl(md, j2), p3 = __shfl(md, j3);
                float w0 = __shfl(invreg, p0 >> 16);
                float w1 = __shfl(invreg, p1 >> 16);
                float w2 = __shfl(invreg, p2 >> 16);
                float w3 = __shfl(invreg, p3 >> 16);
                uint z0 = zb32[((size_t)(p0 >> 16) * N_NODES + (p0 & 0xFFFF)) * 32 + c2];
                uint z1 = zb32[((size_t)(p1 >> 16) * N_NODES + (p1 & 0xFFFF)) * 32 + c2];
                uint z2 = zb32[((size_t)(p2 >> 16) * N_NODES + (p2 & 0xFFFF)) * 32 + c2];
                uint z3 = zb32[((size_t)(p3 >> 16) * N_NODES + (p3 & 0xFFFF)) * 32 + c2];
                ax += w0 * bf_lo(z0) + w1 * bf_lo(z1) + w2 * bf_lo(z2) + w3 * bf_lo(z3);
                ay += w0 * bf_hi(z0) + w1 * bf_hi(z1) + w2 * bf_hi(z2) + w3 * bf_hi(z3);
            }
        }
        for (; i + 8 <= m; i += 8) {
            int j0 = i + eg, j1 = j0 + 2, j2 = j0 + 4, j3 = j0 + 6;
            int p0 = __shfl(md, j0), p1 = __shfl(md, j1);
            int p2 = __shfl(md, j2), p3 = __shfl(md, j3);
            float w0 = __shfl(invreg, p0 >> 16);
            float w1 = __shfl(invreg, p1 >> 16);
            float w2 = __shfl(invreg, p2 >> 16);
            float w3 = __shfl(invreg, p3 >> 16);
            uint z0 = zb32[((size_t)(p0 >> 16) * N_NODES + (p0 & 0xFFFF)) * 32 + c2];
            uint z1 = zb32[((size_t)(p1 >> 16) * N_NODES + (p1 & 0xFFFF)) * 32 + c2];
            uint z2 = zb32[((size_t)(p2 >> 16) * N_NODES + (p2 & 0xFFFF)) * 32 + c2];
            uint z3 = zb32[((size_t)(p3 >> 16) * N_NODES + (p3 & 0xFFFF)) * 32 + c2];
            ax += w0 * bf_lo(z0) + w1 * bf_lo(z1) + w2 * bf_lo(z2) + w3 * bf_lo(z3);
            ay += w0 * bf_hi(z0) + w1 * bf_hi(z1) + w2 * bf_hi(z2) + w3 * bf_hi(z3);
        }
        for (; i < m; i += 2) {
            int ii = i + eg;
            int srcl = (ii < m) ? ii : 0;
            int p = __shfl(md, srcl);
            float w = __shfl(invreg, p >> 16);
            if (ii < m) {
                uint zv = zb32[((size_t)(p >> 16) * N_NODES + (p & 0xFFFF)) * 32 + c2];
                ax += w * bf_lo(zv);
                ay += w * bf_hi(zv);
            }
        }
    }
    ax += __shfl_xor(ax, 32);
    ay += __shfl_xor(ay, 32);
    if (eg == 0) {
        float2* o = (float2*)out + (size_t)n * 32 + c2;
        float2 v = *o;
        v.x += ax; v.y += ay;
        *o = v;
    }
}

extern "C" void kernel_launch(void* const* d_in, const int* in_sizes, int n_in,
                              void* d_out, int out_size, void* d_ws, size_t ws_size,
                              hipStream_t stream) {
    const int*   ei    = (const int*)d_in[0];
    const int*   et    = (const int*)d_in[1];
    const float* W1    = (const float*)d_in[2];
    const float* root1 = (const float*)d_in[3];
    const float* b1    = (const float*)d_in[4];
    const float* W2    = (const float*)d_in[5];
    const float* root2 = (const float*)d_in[6];
    const float* b2    = (const float*)d_in[7];
    float* out = (float*)d_out;

    // ws layout
    int*    cnt     = (int*)d_ws;                   // NR
    int*    segbase = cnt + NR;                     // NR + 16 (sentinel at NR)
    int*    bsum    = segbase + NR + 16;            // 512
    int*    rank    = bsum + 512;                   // E
    int*    em      = rank + N_EDGES;               // E ints
    uint*   h16     = (uint*)(em + N_EDGES);        // N*64
    ushort* w2t     = (ushort*)(h16 + (size_t)N_NODES * 64);  // 9*8192
    ushort* w1b     = w2t + 9 * 8192;               // R*N*H bf16 = 82 MB
    ushort* zb      = w1b + (size_t)N_REL * N_NODES * H_DIM;  // 8*N*64 bf16 = 41 MB

    hipMemsetAsync(cnt, 0, (size_t)NR * sizeof(int), stream);

    build_convert <<<EDGE_NB + W1CVT_NB + W2CVT_NB, 256, 0, stream>>>(
                      ei, et, cnt, rank, W1, w1b, W2, root2, w2t);
    scanA         <<<SCAN_NB, 256, 0, stream>>>(cnt, segbase, bsum);
    scanB         <<<1, 512, 0, stream>>>(bsum, segbase);
    scanC         <<<(NR + 255) / 256, 256, 0, stream>>>(segbase, bsum);
    scatter_kernel<<<(N_EDGES + 255) / 256, 256, 0, stream>>>(ei, et, segbase, rank, em);
    conv1_gather  <<<N_NODES / 4, 256, 0, stream>>>(em, segbase, cnt, w1b, root1, b1, h16);
    zgemm         <<<N_NODES / 64, 256, 0, stream>>>(h16, w2t, b2, zb, out);
    zgather       <<<N_NODES / 4, 256, 0, stream>>>(em, segbase, cnt, (const uint*)zb, out);
}